// Round 15
// baseline (2931.183 us; speedup 1.0000x reference)
//
#include <hip/hip_runtime.h>

// LSTM_88776974008866: bidirectional LSTM (B=2048, S=128, H=512, in=4) + 4 sigmoid heads.
// Round 15: r13 (best passing, 2454us) byte-identical EXCEPT A-prefetch ring depth 4->6
// (more in-flight A bytes to cover L2 latency; numerics unchanged).
// LEDGER (hard-won rules):
//  - 1 protocol-block per CU ONLY: 2 blocks/CU fails correctness deterministically
//    (r9+r14, identical absmax 1.95e-2, two independent implementations).
//  - No agent acquire/release in hot loop: acquire=invl2 (25GB LLC refetch, r3),
//    release-store=wbl2 (525MB HBM flush, r4/r5). Relaxed RMW publish + relaxed load
//    poll + per-step L1-only `buffer_inv sc0` is the validated protocol.
//  - h writes must cover full 64B lines per block (r12: 32B stripes => 513MB writes).
//  - launch_bounds must leave VGPR headroom (r10: forced 64 VGPR => spills => 3.3GB).
//  - XCD-exact groups via HW_REG_XCC_ID + per-XCD rank (r7 disproved bid heuristics).

typedef __attribute__((ext_vector_type(8))) __bf16 bf16x8;
typedef __attribute__((ext_vector_type(4))) float f32x4;
typedef __attribute__((ext_vector_type(8))) unsigned short u16x8;

__device__ __forceinline__ unsigned short f2bf(float f) {
  unsigned u = __float_as_uint(f);
  u += 0x7fffu + ((u >> 16) & 1u);   // round-to-nearest-even
  return (unsigned short)(u >> 16);
}
__device__ __forceinline__ float bf2f(unsigned short s) {
  return __uint_as_float(((unsigned)s) << 16);
}
__device__ __forceinline__ float sigm(float x) { return 1.0f / (1.0f + __expf(-x)); }
__device__ __forceinline__ float tanhfast(float x) {
  float e = __expf(-2.0f * fabsf(x));
  float t = (1.0f - e) / (1.0f + e);
  return x < 0.0f ? -t : t;
}

__device__ __forceinline__ void gl_lds16(const void* g, void* l) {
  __builtin_amdgcn_global_load_lds(
      (const __attribute__((address_space(1))) unsigned int*)g,
      (__attribute__((address_space(3))) unsigned int*)l, 16, 0, 0);
}

// ---------------------------------------------------------------------------
// prep (r8 verbatim): Whh (fp32 [2048][512], gate-major i,f,g,o) -> Wp image:
//   chunk = ((((dir*16+ni)*2+wn)*16+kt)*4+nf)*64 + lhi*16 + l15   (16B chunks)
// wtail[dir][permrow][8] = {wih[0..3], bias, 0,0,0} bf16 for the tail MFMA.
// ---------------------------------------------------------------------------
__global__ __launch_bounds__(256) void prep_k(
    const float* __restrict__ Wf_hh, const float* __restrict__ Wf_ih,
    const float* __restrict__ bf_ih, const float* __restrict__ bf_hh,
    const float* __restrict__ Wb_hh, const float* __restrict__ Wb_ih,
    const float* __restrict__ bb_ih, const float* __restrict__ bb_hh,
    unsigned short* __restrict__ Wp, unsigned short* __restrict__ wtailp)
{
  int flat = blockIdx.x * 256 + threadIdx.x;   // 0 .. 262143
  int l15 = flat & 15;
  int lhi = (flat >> 4) & 3;
  int nf  = (flat >> 6) & 3;
  int kt  = (flat >> 8) & 15;
  int wn  = (flat >> 12) & 1;
  int ni  = (flat >> 13) & 15;
  int dir = (flat >> 17) & 1;
  const float* Whh = dir ? Wb_hh : Wf_hh;
  const float* Wih = dir ? Wb_ih : Wf_ih;
  const float* bih = dir ? bb_ih : bf_ih;
  const float* bhh = dir ? bb_hh : bf_hh;

  int j = ((ni * 2 + wn) << 4) + l15;          // hidden index 0..511
  int orig = (nf << 9) + j;                    // original gate-major row
  int k0 = (kt << 5) + (lhi << 3);
  const float4* src = (const float4*)(Whh + (size_t)orig * 512 + k0);
  float4 a = src[0], b = src[1];
  u16x8 o;
  o[0] = f2bf(a.x); o[1] = f2bf(a.y); o[2] = f2bf(a.z); o[3] = f2bf(a.w);
  o[4] = f2bf(b.x); o[5] = f2bf(b.y); o[6] = f2bf(b.z); o[7] = f2bf(b.w);
  *(u16x8*)(Wp + (size_t)flat * 8) = o;

  if (kt == 0 && lhi == 0) {
    int rg = (ni << 7) + (wn << 6) + (nf << 4) + l15;   // permuted row
    unsigned short* wt = wtailp + (((size_t)(dir << 11) + rg) << 3);
    wt[0] = f2bf(Wih[orig * 4 + 0]);
    wt[1] = f2bf(Wih[orig * 4 + 1]);
    wt[2] = f2bf(Wih[orig * 4 + 2]);
    wt[3] = f2bf(Wih[orig * 4 + 3]);
    wt[4] = f2bf(bih[orig] + bhh[orig]);
    wt[5] = 0; wt[6] = 0; wt[7] = 0;
  }
}

__device__ __forceinline__ void mfma16(const bf16x8 av[4], const bf16x8 bv[4],
                                       f32x4 acc[4][4]) {
#pragma unroll
  for (int mf = 0; mf < 4; ++mf)
#pragma unroll
    for (int nf = 0; nf < 4; ++nf)
      acc[mf][nf] = __builtin_amdgcn_mfma_f32_16x16x32_bf16(av[mf], bv[nf], acc[mf][nf], 0, 0, 0);
}

// ---------------------------------------------------------------------------
// Persistent kernel: 256 blocks x 512 threads (1 block/CU via 128KB LDS),
// cooperative launch => exactly 32 blocks per XCD (pigeonhole at 1/CU).
// Roles: xcc = HW_REG_XCC_ID; rank = per-XCD counter; dir = rank>>4, ni = rank&15.
// The 16 blocks of (xcc,dir) produce/consume one h panel in one physical L2.
// ctrl (uints): [xcc<<5] rank counters; flags at 256 + grp*512 + ni*32
//   (grp = mi*2+dir; per-block single-writer flag, 128B apart).
// ---------------------------------------------------------------------------
__global__ __launch_bounds__(512, 2) void lstm_persist(
    const float* __restrict__ y,
    const unsigned short* __restrict__ Wp,
    const unsigned short* __restrict__ wtailp,
    unsigned short* __restrict__ hf0, unsigned short* __restrict__ hf1,
    unsigned short* __restrict__ hb0, unsigned short* __restrict__ hb1,
    unsigned* __restrict__ ctrl)
{
  __shared__ alignas(16) unsigned short Wl[65536];   // 128 KB W image
  __shared__ unsigned arrive_cnt;
  __shared__ unsigned rank_sh;

  const int tid = threadIdx.x;
  const int w = tid >> 6, lane = tid & 63;

  unsigned xcc;
  asm("s_getreg_b32 %0, hwreg(HW_REG_XCC_ID)" : "=s"(xcc));
  xcc &= 7u;

  if (tid == 0) {
    arrive_cnt = 0u;
    rank_sh = __hip_atomic_fetch_add(ctrl + (xcc << 5), 1u,
                                     __ATOMIC_RELAXED, __HIP_MEMORY_SCOPE_AGENT);
  }
  __syncthreads();
  const int rank = (int)(rank_sh & 31u);
  const int dir = rank >> 4;               // 16 fwd + 16 bwd blocks per XCD
  const int ni  = rank & 15;
  const int mi  = (int)xcc;
  const int bm0 = mi << 8;                 // this XCD's 256 batch rows

  unsigned short* h0 = dir ? hb0 : hf0;
  unsigned short* h1 = dir ? hb1 : hf1;

  const int wm = w >> 1;                   // 0..3: 64-row quarter
  const int wn = w & 1;                    // 0..1: 64-col half
  const int l15 = lane & 15;
  const int lhi = lane >> 4;

  // ---- one-time: copy this block's 128KB W image into LDS (contiguous) ----
  const unsigned short* Wblk = Wp + ((size_t)((dir << 4) | ni) << 16);
#pragma unroll
  for (int i = 0; i < 16; ++i) {
    gl_lds16(Wblk + (size_t)(((i << 9) + tid)) * 8,
             (unsigned short*)Wl + ((i << 12) + (w << 9)));
  }

  // ---- tail B-fragments (wih + bias), register-resident (r8 verbatim) ----
  bf16x8 btail[4];
#pragma unroll
  for (int nf = 0; nf < 4; ++nf) {
    u16x8 wt = *(const u16x8*)(wtailp +
        (((size_t)(dir << 11) + ((ni << 7) | (wn << 6) | (nf << 4) | l15))) * 8);
    u16x8 z = {};
    u16x8 sel = (lhi == 0) ? wt : z;
    btail[nf] = *(bf16x8*)&sel;
  }

  const int j = (((ni << 1) + wn) << 4) + l15;   // hidden index 0..511
  float c_reg[16];
#pragma unroll
  for (int i = 0; i < 16; ++i) c_reg[i] = 0.f;

  const float4* y4 = (const float4*)y;
  unsigned* gflags = ctrl + 256 + (((unsigned)((mi << 1) | dir)) << 9); // 16 flags x 32 u
  unsigned* myflag = gflags + (ni << 5);                               // single writer

  // LDS B-fragment base for this wave (contiguous 1KB per (kt,nf) read)
  const unsigned short* wB = Wl + (wn << 15) + (lane << 3);

  __syncthreads();   // Wl ready (drains global_load_lds)

  const unsigned short* hin = h0;
  unsigned short* hout = h1;

#pragma unroll 1
  for (int t = 0; t < 128; ++t) {
    const int t_eff = dir ? (127 - t) : t;

    // ---- x loads (independent of the flag) ----
    float4 xr[4];
#pragma unroll
    for (int mf = 0; mf < 4; ++mf)
      xr[mf] = y4[(size_t)(bm0 + (wm << 6) + (mf << 4) + l15) * 128 + t_eff];

    // ---- parallel poll: lanes 0-15 of wave0 LOAD all 16 peer flags at once ----
    if (t) {
      if (w == 0) {
        const unsigned* fp = gflags + ((lane & 15) << 5);
        while (true) {
          unsigned v = 0;
          if (lane < 16)
            v = __hip_atomic_load(fp, __ATOMIC_RELAXED, __HIP_MEMORY_SCOPE_AGENT);
          bool ok = (lane < 16) ? (v >= (unsigned)t) : true;
          if (__all(ok)) break;
          __builtin_amdgcn_s_sleep(2);
        }
      }
      __syncthreads();
      asm volatile("buffer_inv sc0\n\ts_waitcnt vmcnt(0)" ::: "memory");
    }

    f32x4 acc[4][4];
#pragma unroll
    for (int a = 0; a < 4; ++a)
#pragma unroll
      for (int b = 0; b < 4; ++b) acc[a][b] = (f32x4){0.f, 0.f, 0.f, 0.f};

    if (t) {
      const unsigned short* aBase =
          hin + ((size_t)(bm0 + (wm << 6) + l15) << 9) + (lhi << 3);

      bf16x8 aA[6][4], bT[2][4];   // A ring depth 6 (r15's single change vs r13)

      // slice rotation: block ni starts its k-sweep at slice ni (load-order only)
#define SL(i) ((ni + (i)) & 15)
#define ALOAD(kk, sl)                                                          \
      do {                                                                     \
        const unsigned short* ap_ = aBase + ((kk) << 5);                       \
        aA[sl][0] = *(const bf16x8*)(ap_);                                     \
        aA[sl][1] = *(const bf16x8*)(ap_ + (16 << 9));                         \
        aA[sl][2] = *(const bf16x8*)(ap_ + (32 << 9));                         \
        aA[sl][3] = *(const bf16x8*)(ap_ + (48 << 9));                         \
      } while (0)
#define BLOAD(kk, sl)                                                          \
      do {                                                                     \
        const unsigned short* bp_ = wB + ((kk) << 11);                         \
        bT[sl][0] = *(const bf16x8*)(bp_);                                     \
        bT[sl][1] = *(const bf16x8*)(bp_ + 512);                               \
        bT[sl][2] = *(const bf16x8*)(bp_ + 1024);                              \
        bT[sl][3] = *(const bf16x8*)(bp_ + 1536);                              \
      } while (0)

      // prologue: A slices 0..5 (rotated), B slices 0..1 (rotated)
      ALOAD(SL(0), 0); ALOAD(SL(1), 1); ALOAD(SL(2), 2);
      ALOAD(SL(3), 3); ALOAD(SL(4), 4); ALOAD(SL(5), 5);
      BLOAD(SL(0), 0); BLOAD(SL(1), 1);

      // tail MFMA (x*Wih + bias) FIRST, while prologue loads are in flight
      {
        bf16x8 atail[4];
#pragma unroll
        for (int mf = 0; mf < 4; ++mf) {
          u16x8 at = {};
          if (lhi == 0) {
            at[0] = f2bf(xr[mf].x); at[1] = f2bf(xr[mf].y);
            at[2] = f2bf(xr[mf].z); at[3] = f2bf(xr[mf].w);
            at[4] = 0x3F80;   // 1.0 -> picks up bias row
          }
          atail[mf] = *(bf16x8*)&at;
        }
        mfma16(atail, btail, acc);
      }

#pragma unroll
      for (int i = 0; i < 16; ++i) {
        __builtin_amdgcn_s_setprio(1);
        mfma16(aA[i % 6], bT[i & 1], acc);
        __builtin_amdgcn_s_setprio(0);
        if (i < 10) ALOAD(SL(i + 6), (i + 6) % 6);   // slices 6..15
        if (i < 14) BLOAD(SL(i + 2), i & 1);
      }
#undef ALOAD
#undef BLOAD
#undef SL
    } else {
      // t=0: h=0, GEMM skipped; just tail
      bf16x8 atail[4];
#pragma unroll
      for (int mf = 0; mf < 4; ++mf) {
        u16x8 at = {};
        if (lhi == 0) {
          at[0] = f2bf(xr[mf].x); at[1] = f2bf(xr[mf].y);
          at[2] = f2bf(xr[mf].z); at[3] = f2bf(xr[mf].w);
          at[4] = 0x3F80;
        }
        atail[mf] = *(bf16x8*)&at;
      }
      mfma16(atail, btail, acc);
    }

    // ---- epilogue: lane-local LSTM cell update, c in registers ----
#pragma unroll
    for (int mf = 0; mf < 4; ++mf) {
#pragma unroll
      for (int r = 0; r < 4; ++r) {
        const float ig = sigm(acc[mf][0][r]);
        const float fg = sigm(acc[mf][1][r]);
        const float gg = tanhfast(acc[mf][2][r]);
        const float og = sigm(acc[mf][3][r]);
        const float cn = fg * c_reg[mf * 4 + r] + ig * gg;
        c_reg[mf * 4 + r] = cn;
        const int b = bm0 + (wm << 6) + (mf << 4) + (lhi << 2) + r;
        hout[((size_t)b << 9) + j] = f2bf(og * tanhfast(cn));
      }
    }

    // ---- publish: per-wave store drain -> LDS arrival -> 8th wave bumps OWN flag ----
    if (t != 127) {
      asm volatile("s_waitcnt vmcnt(0)" ::: "memory");   // own h stores in L2
      if (lane == 0) {
        unsigned old = atomicAdd(&arrive_cnt, 1u);       // intra-block LDS atomic
        if (old == (unsigned)((t << 3) + 7)) {           // last of 8 waves this step
          __hip_atomic_fetch_add(myflag, 1u, __ATOMIC_RELAXED,
                                 __HIP_MEMORY_SCOPE_AGENT);
        }
      }
    }

    const unsigned short* tmp = hin; hin = hout; hout = (unsigned short*)tmp;
  }
}

// ---------------------------------------------------------------------------
// heads: out[b][k] = sigmoid(hf[b]·Wk[0:512] + hb[b]·Wk[512:1024] + bk)
// ---------------------------------------------------------------------------
__global__ __launch_bounds__(256) void heads_k(
    const unsigned short* __restrict__ hf, const unsigned short* __restrict__ hb,
    const float* __restrict__ W1, const float* __restrict__ b1,
    const float* __restrict__ W2, const float* __restrict__ b2,
    const float* __restrict__ W3, const float* __restrict__ b3,
    const float* __restrict__ W4, const float* __restrict__ b4,
    float* __restrict__ out)
{
  const int wid = threadIdx.x >> 6, lane = threadIdx.x & 63;
  const int b = blockIdx.x * 4 + wid;
  const unsigned short* src = (lane < 32) ? (hf + ((size_t)b << 9) + (lane << 4))
                                          : (hb + ((size_t)b << 9) + ((lane - 32) << 4));
  const int woff = lane << 4;
  u16x8 v0 = *(const u16x8*)src;
  u16x8 v1 = *(const u16x8*)(src + 8);
  float hv[16];
#pragma unroll
  for (int e = 0; e < 8; ++e) { hv[e] = bf2f(v0[e]); hv[8 + e] = bf2f(v1[e]); }
  float s0 = 0.f, s1 = 0.f, s2 = 0.f, s3 = 0.f;
#pragma unroll
  for (int e = 0; e < 16; ++e) {
    float h = hv[e];
    s0 += h * W1[woff + e];
    s1 += h * W2[woff + e];
    s2 += h * W3[woff + e];
    s3 += h * W4[woff + e];
  }
#pragma unroll
  for (int off = 32; off >= 1; off >>= 1) {
    s0 += __shfl_xor(s0, off, 64);
    s1 += __shfl_xor(s1, off, 64);
    s2 += __shfl_xor(s2, off, 64);
    s3 += __shfl_xor(s3, off, 64);
  }
  if (lane == 0) {
    out[b * 4 + 0] = sigm(s0 + b1[0]);
    out[b * 4 + 1] = sigm(s1 + b2[0]);
    out[b * 4 + 2] = sigm(s2 + b3[0]);
    out[b * 4 + 3] = sigm(s3 + b4[0]);
  }
}

// ---------------------------------------------------------------------------
extern "C" void kernel_launch(void* const* d_in, const int* in_sizes, int n_in,
                              void* d_out, int out_size, void* d_ws, size_t ws_size,
                              hipStream_t stream) {
  (void)in_sizes; (void)n_in; (void)out_size; (void)ws_size;
  const float* y     = (const float*)d_in[0];
  const float* Wf_ih = (const float*)d_in[1];
  const float* Wf_hh = (const float*)d_in[2];
  const float* bf_ih = (const float*)d_in[3];
  const float* bf_hh = (const float*)d_in[4];
  const float* Wb_ih = (const float*)d_in[5];
  const float* Wb_hh = (const float*)d_in[6];
  const float* bb_ih = (const float*)d_in[7];
  const float* bb_hh = (const float*)d_in[8];
  const float* W1 = (const float*)d_in[9];  const float* b1 = (const float*)d_in[10];
  const float* W2 = (const float*)d_in[11]; const float* b2 = (const float*)d_in[12];
  const float* W3 = (const float*)d_in[13]; const float* b3 = (const float*)d_in[14];
  const float* W4 = (const float*)d_in[15]; const float* b4 = (const float*)d_in[16];

  char* ws = (char*)d_ws;
  const size_t MB = 1ull << 20;
  unsigned short* Wp    = (unsigned short*)(ws);            // 4MB: per-(dir,ni) LDS images
  unsigned short* hf0   = (unsigned short*)(ws + 4 * MB);   // 2MB
  unsigned short* hb0   = (unsigned short*)(ws + 6 * MB);   // 2MB
  unsigned short* hf1   = (unsigned short*)(ws + 8 * MB);   // 2MB
  unsigned short* hb1   = (unsigned short*)(ws + 10 * MB);  // 2MB
  unsigned short* wtail = (unsigned short*)(ws + 12 * MB);  // 64KB
  unsigned* ctrl        = (unsigned*)(ws + 13 * MB);        // rank counters + 256 flags

  hipMemsetAsync(ws + 4 * MB, 0, 4 * MB, stream);    // hf0+hb0 = h(t=0) zeros
  hipMemsetAsync(ws + 13 * MB, 0, 65536, stream);    // ctrl: counters + flags

  prep_k<<<1024, 256, 0, stream>>>(Wf_hh, Wf_ih, bf_ih, bf_hh,
                                   Wb_hh, Wb_ih, bb_ih, bb_hh,
                                   Wp, wtail);

  void* args[] = { (void*)&y, (void*)&Wp, (void*)&wtail,
                   (void*)&hf0, (void*)&hf1, (void*)&hb0, (void*)&hb1, (void*)&ctrl };
  hipLaunchCooperativeKernel((const void*)lstm_persist, dim3(256), dim3(512),
                             args, 0, stream);

  // 128 steps (even): final h is in buffer 0 for both directions
  heads_k<<<512, 256, 0, stream>>>(hf0, hb0, W1, b1, W2, b2, W3, b3, W4, b4,
                                   (float*)d_out);
}

// Round 16
// 2436.884 us; speedup vs baseline: 1.2028x; 1.2028x over previous
//
#include <hip/hip_runtime.h>

// LSTM_88776974008866: bidirectional LSTM (B=2048, S=128, H=512, in=4) + 4 sigmoid heads.
// Round 16: restore r13 (best passing, 2454us) + two safe micro-tweaks:
//  (a) tail MFMA (x*Wih+bias; register-only inputs) hoisted BEFORE the flag poll so it
//      overlaps the wait. Accumulation order unchanged -> absmax identical.
//  (b) poll sleep quantum 2 -> 1 (faster flag pickup).
// LEDGER (hard-won rules):
//  - 1 protocol-block per CU ONLY (r9+r14: 2 blocks/CU fails, absmax 1.95e-2, twice).
//  - A-ring depth > 4 spills at 512thr/128KB-LDS (r15: 1.4GB scratch writes). Depth 4 max.
//  - No agent acquire/release in hot loop: acquire=invl2 (25GB refetch, r3),
//    release-store=wbl2 (525MB flush, r4/r5). Relaxed RMW publish + relaxed load poll +
//    per-step L1-only `buffer_inv sc0` is the validated protocol.
//  - h writes must cover full 64B lines per block (r12: 32B stripes => 513MB writes).
//  - launch_bounds must leave VGPR headroom (r10: forced 64 VGPR => spills => 3.3GB).
//  - XCD-exact groups via HW_REG_XCC_ID + per-XCD rank (r7 disproved bid heuristics).

typedef __attribute__((ext_vector_type(8))) __bf16 bf16x8;
typedef __attribute__((ext_vector_type(4))) float f32x4;
typedef __attribute__((ext_vector_type(8))) unsigned short u16x8;

__device__ __forceinline__ unsigned short f2bf(float f) {
  unsigned u = __float_as_uint(f);
  u += 0x7fffu + ((u >> 16) & 1u);   // round-to-nearest-even
  return (unsigned short)(u >> 16);
}
__device__ __forceinline__ float bf2f(unsigned short s) {
  return __uint_as_float(((unsigned)s) << 16);
}
__device__ __forceinline__ float sigm(float x) { return 1.0f / (1.0f + __expf(-x)); }
__device__ __forceinline__ float tanhfast(float x) {
  float e = __expf(-2.0f * fabsf(x));
  float t = (1.0f - e) / (1.0f + e);
  return x < 0.0f ? -t : t;
}

__device__ __forceinline__ void gl_lds16(const void* g, void* l) {
  __builtin_amdgcn_global_load_lds(
      (const __attribute__((address_space(1))) unsigned int*)g,
      (__attribute__((address_space(3))) unsigned int*)l, 16, 0, 0);
}

// ---------------------------------------------------------------------------
// prep (r8 verbatim): Whh (fp32 [2048][512], gate-major i,f,g,o) -> Wp image:
//   chunk = ((((dir*16+ni)*2+wn)*16+kt)*4+nf)*64 + lhi*16 + l15   (16B chunks)
// wtail[dir][permrow][8] = {wih[0..3], bias, 0,0,0} bf16 for the tail MFMA.
// ---------------------------------------------------------------------------
__global__ __launch_bounds__(256) void prep_k(
    const float* __restrict__ Wf_hh, const float* __restrict__ Wf_ih,
    const float* __restrict__ bf_ih, const float* __restrict__ bf_hh,
    const float* __restrict__ Wb_hh, const float* __restrict__ Wb_ih,
    const float* __restrict__ bb_ih, const float* __restrict__ bb_hh,
    unsigned short* __restrict__ Wp, unsigned short* __restrict__ wtailp)
{
  int flat = blockIdx.x * 256 + threadIdx.x;   // 0 .. 262143
  int l15 = flat & 15;
  int lhi = (flat >> 4) & 3;
  int nf  = (flat >> 6) & 3;
  int kt  = (flat >> 8) & 15;
  int wn  = (flat >> 12) & 1;
  int ni  = (flat >> 13) & 15;
  int dir = (flat >> 17) & 1;
  const float* Whh = dir ? Wb_hh : Wf_hh;
  const float* Wih = dir ? Wb_ih : Wf_ih;
  const float* bih = dir ? bb_ih : bf_ih;
  const float* bhh = dir ? bb_hh : bf_hh;

  int j = ((ni * 2 + wn) << 4) + l15;          // hidden index 0..511
  int orig = (nf << 9) + j;                    // original gate-major row
  int k0 = (kt << 5) + (lhi << 3);
  const float4* src = (const float4*)(Whh + (size_t)orig * 512 + k0);
  float4 a = src[0], b = src[1];
  u16x8 o;
  o[0] = f2bf(a.x); o[1] = f2bf(a.y); o[2] = f2bf(a.z); o[3] = f2bf(a.w);
  o[4] = f2bf(b.x); o[5] = f2bf(b.y); o[6] = f2bf(b.z); o[7] = f2bf(b.w);
  *(u16x8*)(Wp + (size_t)flat * 8) = o;

  if (kt == 0 && lhi == 0) {
    int rg = (ni << 7) + (wn << 6) + (nf << 4) + l15;   // permuted row
    unsigned short* wt = wtailp + (((size_t)(dir << 11) + rg) << 3);
    wt[0] = f2bf(Wih[orig * 4 + 0]);
    wt[1] = f2bf(Wih[orig * 4 + 1]);
    wt[2] = f2bf(Wih[orig * 4 + 2]);
    wt[3] = f2bf(Wih[orig * 4 + 3]);
    wt[4] = f2bf(bih[orig] + bhh[orig]);
    wt[5] = 0; wt[6] = 0; wt[7] = 0;
  }
}

__device__ __forceinline__ void mfma16(const bf16x8 av[4], const bf16x8 bv[4],
                                       f32x4 acc[4][4]) {
#pragma unroll
  for (int mf = 0; mf < 4; ++mf)
#pragma unroll
    for (int nf = 0; nf < 4; ++nf)
      acc[mf][nf] = __builtin_amdgcn_mfma_f32_16x16x32_bf16(av[mf], bv[nf], acc[mf][nf], 0, 0, 0);
}

// ---------------------------------------------------------------------------
// Persistent kernel: 256 blocks x 512 threads (1 block/CU via 128KB LDS),
// cooperative launch => exactly 32 blocks per XCD (pigeonhole at 1/CU).
// Roles: xcc = HW_REG_XCC_ID; rank = per-XCD counter; dir = rank>>4, ni = rank&15.
// The 16 blocks of (xcc,dir) produce/consume one h panel in one physical L2.
// ctrl (uints): [xcc<<5] rank counters; flags at 256 + grp*512 + ni*32
//   (grp = mi*2+dir; per-block single-writer flag, 128B apart).
// ---------------------------------------------------------------------------
__global__ __launch_bounds__(512, 2) void lstm_persist(
    const float* __restrict__ y,
    const unsigned short* __restrict__ Wp,
    const unsigned short* __restrict__ wtailp,
    unsigned short* __restrict__ hf0, unsigned short* __restrict__ hf1,
    unsigned short* __restrict__ hb0, unsigned short* __restrict__ hb1,
    unsigned* __restrict__ ctrl)
{
  __shared__ alignas(16) unsigned short Wl[65536];   // 128 KB W image
  __shared__ unsigned arrive_cnt;
  __shared__ unsigned rank_sh;

  const int tid = threadIdx.x;
  const int w = tid >> 6, lane = tid & 63;

  unsigned xcc;
  asm("s_getreg_b32 %0, hwreg(HW_REG_XCC_ID)" : "=s"(xcc));
  xcc &= 7u;

  if (tid == 0) {
    arrive_cnt = 0u;
    rank_sh = __hip_atomic_fetch_add(ctrl + (xcc << 5), 1u,
                                     __ATOMIC_RELAXED, __HIP_MEMORY_SCOPE_AGENT);
  }
  __syncthreads();
  const int rank = (int)(rank_sh & 31u);
  const int dir = rank >> 4;               // 16 fwd + 16 bwd blocks per XCD
  const int ni  = rank & 15;
  const int mi  = (int)xcc;
  const int bm0 = mi << 8;                 // this XCD's 256 batch rows

  unsigned short* h0 = dir ? hb0 : hf0;
  unsigned short* h1 = dir ? hb1 : hf1;

  const int wm = w >> 1;                   // 0..3: 64-row quarter
  const int wn = w & 1;                    // 0..1: 64-col half
  const int l15 = lane & 15;
  const int lhi = lane >> 4;

  // ---- one-time: copy this block's 128KB W image into LDS (contiguous) ----
  const unsigned short* Wblk = Wp + ((size_t)((dir << 4) | ni) << 16);
#pragma unroll
  for (int i = 0; i < 16; ++i) {
    gl_lds16(Wblk + (size_t)(((i << 9) + tid)) * 8,
             (unsigned short*)Wl + ((i << 12) + (w << 9)));
  }

  // ---- tail B-fragments (wih + bias), register-resident (r8 verbatim) ----
  bf16x8 btail[4];
#pragma unroll
  for (int nf = 0; nf < 4; ++nf) {
    u16x8 wt = *(const u16x8*)(wtailp +
        (((size_t)(dir << 11) + ((ni << 7) | (wn << 6) | (nf << 4) | l15))) * 8);
    u16x8 z = {};
    u16x8 sel = (lhi == 0) ? wt : z;
    btail[nf] = *(bf16x8*)&sel;
  }

  const int j = (((ni << 1) + wn) << 4) + l15;   // hidden index 0..511
  float c_reg[16];
#pragma unroll
  for (int i = 0; i < 16; ++i) c_reg[i] = 0.f;

  const float4* y4 = (const float4*)y;
  unsigned* gflags = ctrl + 256 + (((unsigned)((mi << 1) | dir)) << 9); // 16 flags x 32 u
  unsigned* myflag = gflags + (ni << 5);                               // single writer

  // LDS B-fragment base for this wave (contiguous 1KB per (kt,nf) read)
  const unsigned short* wB = Wl + (wn << 15) + (lane << 3);

  __syncthreads();   // Wl ready (drains global_load_lds)

  const unsigned short* hin = h0;
  unsigned short* hout = h1;

#pragma unroll 1
  for (int t = 0; t < 128; ++t) {
    const int t_eff = dir ? (127 - t) : t;

    // ---- x loads + tail MFMA BEFORE the poll (register-only inputs; overlaps
    //      the wait; accumulation order identical to r13: tail first) ----
    f32x4 acc[4][4];
#pragma unroll
    for (int a = 0; a < 4; ++a)
#pragma unroll
      for (int b = 0; b < 4; ++b) acc[a][b] = (f32x4){0.f, 0.f, 0.f, 0.f};
    {
      bf16x8 atail[4];
#pragma unroll
      for (int mf = 0; mf < 4; ++mf) {
        float4 x4 = y4[(size_t)(bm0 + (wm << 6) + (mf << 4) + l15) * 128 + t_eff];
        u16x8 at = {};
        if (lhi == 0) {
          at[0] = f2bf(x4.x); at[1] = f2bf(x4.y);
          at[2] = f2bf(x4.z); at[3] = f2bf(x4.w);
          at[4] = 0x3F80;   // 1.0 -> picks up bias row
        }
        atail[mf] = *(bf16x8*)&at;
      }
      mfma16(atail, btail, acc);
    }

    // ---- parallel poll: lanes 0-15 of wave0 LOAD all 16 peer flags at once ----
    if (t) {
      if (w == 0) {
        const unsigned* fp = gflags + ((lane & 15) << 5);
        while (true) {
          unsigned v = 0;
          if (lane < 16)
            v = __hip_atomic_load(fp, __ATOMIC_RELAXED, __HIP_MEMORY_SCOPE_AGENT);
          bool ok = (lane < 16) ? (v >= (unsigned)t) : true;
          if (__all(ok)) break;
          __builtin_amdgcn_s_sleep(1);
        }
      }
      __syncthreads();
      asm volatile("buffer_inv sc0\n\ts_waitcnt vmcnt(0)" ::: "memory");

      const unsigned short* aBase =
          hin + ((size_t)(bm0 + (wm << 6) + l15) << 9) + (lhi << 3);

      bf16x8 aA[4][4], bT[2][4];

      // slice rotation: block ni starts its k-sweep at slice ni (load-order only)
#define SL(i) ((ni + (i)) & 15)
#define ALOAD(kk, sl)                                                          \
      do {                                                                     \
        const unsigned short* ap_ = aBase + ((kk) << 5);                       \
        aA[sl][0] = *(const bf16x8*)(ap_);                                     \
        aA[sl][1] = *(const bf16x8*)(ap_ + (16 << 9));                         \
        aA[sl][2] = *(const bf16x8*)(ap_ + (32 << 9));                         \
        aA[sl][3] = *(const bf16x8*)(ap_ + (48 << 9));                         \
      } while (0)
#define BLOAD(kk, sl)                                                          \
      do {                                                                     \
        const unsigned short* bp_ = wB + ((kk) << 11);                         \
        bT[sl][0] = *(const bf16x8*)(bp_);                                     \
        bT[sl][1] = *(const bf16x8*)(bp_ + 512);                               \
        bT[sl][2] = *(const bf16x8*)(bp_ + 1024);                              \
        bT[sl][3] = *(const bf16x8*)(bp_ + 1536);                              \
      } while (0)

      // prologue: A slices 0..3 (rotated), B slices 0..1 (rotated)
      ALOAD(SL(0), 0); ALOAD(SL(1), 1); ALOAD(SL(2), 2); ALOAD(SL(3), 3);
      BLOAD(SL(0), 0); BLOAD(SL(1), 1);

#pragma unroll
      for (int i = 0; i < 16; ++i) {
        __builtin_amdgcn_s_setprio(1);
        mfma16(aA[i & 3], bT[i & 1], acc);
        __builtin_amdgcn_s_setprio(0);
        if (i < 12) ALOAD(SL(i + 4), (i + 4) & 3);
        if (i < 14) BLOAD(SL(i + 2), i & 1);
      }
#undef ALOAD
#undef BLOAD
#undef SL
    }

    // ---- epilogue: lane-local LSTM cell update, c in registers ----
#pragma unroll
    for (int mf = 0; mf < 4; ++mf) {
#pragma unroll
      for (int r = 0; r < 4; ++r) {
        const float ig = sigm(acc[mf][0][r]);
        const float fg = sigm(acc[mf][1][r]);
        const float gg = tanhfast(acc[mf][2][r]);
        const float og = sigm(acc[mf][3][r]);
        const float cn = fg * c_reg[mf * 4 + r] + ig * gg;
        c_reg[mf * 4 + r] = cn;
        const int b = bm0 + (wm << 6) + (mf << 4) + (lhi << 2) + r;
        hout[((size_t)b << 9) + j] = f2bf(og * tanhfast(cn));
      }
    }

    // ---- publish: per-wave store drain -> LDS arrival -> 8th wave bumps OWN flag ----
    if (t != 127) {
      asm volatile("s_waitcnt vmcnt(0)" ::: "memory");   // own h stores in L2
      if (lane == 0) {
        unsigned old = atomicAdd(&arrive_cnt, 1u);       // intra-block LDS atomic
        if (old == (unsigned)((t << 3) + 7)) {           // last of 8 waves this step
          __hip_atomic_fetch_add(myflag, 1u, __ATOMIC_RELAXED,
                                 __HIP_MEMORY_SCOPE_AGENT);
        }
      }
    }

    const unsigned short* tmp = hin; hin = hout; hout = (unsigned short*)tmp;
  }
}

// ---------------------------------------------------------------------------
// heads: out[b][k] = sigmoid(hf[b]·Wk[0:512] + hb[b]·Wk[512:1024] + bk)
// ---------------------------------------------------------------------------
__global__ __launch_bounds__(256) void heads_k(
    const unsigned short* __restrict__ hf, const unsigned short* __restrict__ hb,
    const float* __restrict__ W1, const float* __restrict__ b1,
    const float* __restrict__ W2, const float* __restrict__ b2,
    const float* __restrict__ W3, const float* __restrict__ b3,
    const float* __restrict__ W4, const float* __restrict__ b4,
    float* __restrict__ out)
{
  const int wid = threadIdx.x >> 6, lane = threadIdx.x & 63;
  const int b = blockIdx.x * 4 + wid;
  const unsigned short* src = (lane < 32) ? (hf + ((size_t)b << 9) + (lane << 4))
                                          : (hb + ((size_t)b << 9) + ((lane - 32) << 4));
  const int woff = lane << 4;
  u16x8 v0 = *(const u16x8*)src;
  u16x8 v1 = *(const u16x8*)(src + 8);
  float hv[16];
#pragma unroll
  for (int e = 0; e < 8; ++e) { hv[e] = bf2f(v0[e]); hv[8 + e] = bf2f(v1[e]); }
  float s0 = 0.f, s1 = 0.f, s2 = 0.f, s3 = 0.f;
#pragma unroll
  for (int e = 0; e < 16; ++e) {
    float h = hv[e];
    s0 += h * W1[woff + e];
    s1 += h * W2[woff + e];
    s2 += h * W3[woff + e];
    s3 += h * W4[woff + e];
  }
#pragma unroll
  for (int off = 32; off >= 1; off >>= 1) {
    s0 += __shfl_xor(s0, off, 64);
    s1 += __shfl_xor(s1, off, 64);
    s2 += __shfl_xor(s2, off, 64);
    s3 += __shfl_xor(s3, off, 64);
  }
  if (lane == 0) {
    out[b * 4 + 0] = sigm(s0 + b1[0]);
    out[b * 4 + 1] = sigm(s1 + b2[0]);
    out[b * 4 + 2] = sigm(s2 + b3[0]);
    out[b * 4 + 3] = sigm(s3 + b4[0]);
  }
}

// ---------------------------------------------------------------------------
extern "C" void kernel_launch(void* const* d_in, const int* in_sizes, int n_in,
                              void* d_out, int out_size, void* d_ws, size_t ws_size,
                              hipStream_t stream) {
  (void)in_sizes; (void)n_in; (void)out_size; (void)ws_size;
  const float* y     = (const float*)d_in[0];
  const float* Wf_ih = (const float*)d_in[1];
  const float* Wf_hh = (const float*)d_in[2];
  const float* bf_ih = (const float*)d_in[3];
  const float* bf_hh = (const float*)d_in[4];
  const float* Wb_ih = (const float*)d_in[5];
  const float* Wb_hh = (const float*)d_in[6];
  const float* bb_ih = (const float*)d_in[7];
  const float* bb_hh = (const float*)d_in[8];
  const float* W1 = (const float*)d_in[9];  const float* b1 = (const float*)d_in[10];
  const float* W2 = (const float*)d_in[11]; const float* b2 = (const float*)d_in[12];
  const float* W3 = (const float*)d_in[13]; const float* b3 = (const float*)d_in[14];
  const float* W4 = (const float*)d_in[15]; const float* b4 = (const float*)d_in[16];

  char* ws = (char*)d_ws;
  const size_t MB = 1ull << 20;
  unsigned short* Wp    = (unsigned short*)(ws);            // 4MB: per-(dir,ni) LDS images
  unsigned short* hf0   = (unsigned short*)(ws + 4 * MB);   // 2MB
  unsigned short* hb0   = (unsigned short*)(ws + 6 * MB);   // 2MB
  unsigned short* hf1   = (unsigned short*)(ws + 8 * MB);   // 2MB
  unsigned short* hb1   = (unsigned short*)(ws + 10 * MB);  // 2MB
  unsigned short* wtail = (unsigned short*)(ws + 12 * MB);  // 64KB
  unsigned* ctrl        = (unsigned*)(ws + 13 * MB);        // rank counters + 256 flags

  hipMemsetAsync(ws + 4 * MB, 0, 4 * MB, stream);    // hf0+hb0 = h(t=0) zeros
  hipMemsetAsync(ws + 13 * MB, 0, 65536, stream);    // ctrl: counters + flags

  prep_k<<<1024, 256, 0, stream>>>(Wf_hh, Wf_ih, bf_ih, bf_hh,
                                   Wb_hh, Wb_ih, bb_ih, bb_hh,
                                   Wp, wtail);

  void* args[] = { (void*)&y, (void*)&Wp, (void*)&wtail,
                   (void*)&hf0, (void*)&hf1, (void*)&hb0, (void*)&hb1, (void*)&ctrl };
  hipLaunchCooperativeKernel((const void*)lstm_persist, dim3(256), dim3(512),
                             args, 0, stream);

  // 128 steps (even): final h is in buffer 0 for both directions
  heads_k<<<512, 256, 0, stream>>>(hf0, hb0, W1, b1, W2, b2, W3, b3, W4, b4,
                                   (float*)d_out);
}